// Round 1
// baseline (793.351 us; speedup 1.0000x reference)
//
#include <hip/hip_runtime.h>

#define B_TOT 32768
#define T_OBS 64
#define F_FUT 64
#define S_DIM 5
#define H_DIM 128
#define A_DIM 16
#define R_BLK 64
#define NTHREADS 512
#define XSTR 320     // T*S row stride of obs/target
#define HPAD 132     // h LDS row stride (shorts): 264 B -> bank stride 2, conflict-free b64
#define XPAD 36      // x LDS row stride: 72 B -> conflict-free
#define APAD 24      // adapter LDS row stride: 48 B, 8B-aligned

typedef __attribute__((ext_vector_type(8))) short short8;
typedef __attribute__((ext_vector_type(4))) float f32x4;

union U8 { short8 v; unsigned int u[4]; unsigned short s[8]; };

__device__ __forceinline__ unsigned short f2bf(float f) {
  unsigned int u = __float_as_uint(f);
  u += 0x7FFFu + ((u >> 16) & 1u);   // RNE
  return (unsigned short)(u >> 16);
}

__device__ __forceinline__ f32x4 MFMA(short8 a, short8 b, f32x4 c) {
  return __builtin_amdgcn_mfma_f32_16x16x32_bf16(a, b, c, 0, 0, 0);
}

__device__ __forceinline__ float sigm(float x) {
  return __builtin_amdgcn_rcpf(1.0f + __expf(-x));
}
__device__ __forceinline__ float tanh_(float x) {
  return 2.0f * __builtin_amdgcn_rcpf(1.0f + __expf(-2.0f * x)) - 1.0f;
}

// A-fragment: rows g0+lr of row-major W[.][ld]; k = 32*ks + 16*(i>>2) + 4*lg + (i&3)
__device__ __forceinline__ short8 load_w(const float* __restrict__ W, int ld,
                                         int g0, int gmax, int kmax, int ks,
                                         int lr, int lg) {
  U8 a;
  const int g = g0 + lr;
  #pragma unroll
  for (int i = 0; i < 8; ++i) {
    int k = 32 * ks + 16 * (i >> 2) + 4 * lg + (i & 3);
    float v = (g < gmax && k < kmax) ? W[g * ld + k] : 0.0f;
    a.s[i] = f2bf(v);
  }
  return a.v;
}

__device__ __forceinline__ void ld_bfrag(U8& b, const unsigned short* p) {
  uint2 t0 = *(const uint2*)p;
  uint2 t1 = *(const uint2*)(p + 16);
  b.u[0] = t0.x; b.u[1] = t0.y; b.u[2] = t1.x; b.u[3] = t1.y;
}

__device__ __forceinline__ void gru_step(
    const unsigned short* __restrict__ hb, const unsigned short* __restrict__ xb,
    const short8 (&fh)[3][4], const short8 (&fx)[3],
    const f32x4& brz0, const f32x4& brz1, const f32x4& bnh, const f32x4& bnx,
    const float (&h_old)[4][4], float (&hn)[4][4], int lr, int lg)
{
  f32x4 aR[4], aZ[4], aN[4], aX[4];
  #pragma unroll
  for (int rt = 0; rt < 4; ++rt) {
    const unsigned short* hp = hb + (rt * 16 + lr) * HPAD + 4 * lg;
    const unsigned short* xp = xb + (rt * 16 + lr) * XPAD + 4 * lg;
    U8 bx;
    { uint2 t = *(const uint2*)xp; bx.u[0] = t.x; bx.u[1] = t.y; bx.u[2] = 0u; bx.u[3] = 0u; }
    U8 bh0; ld_bfrag(bh0, hp);
    aR[rt] = MFMA(fh[0][0], bh0.v, brz0);
    aZ[rt] = MFMA(fh[1][0], bh0.v, brz1);
    aN[rt] = MFMA(fh[2][0], bh0.v, bnh);
    #pragma unroll
    for (int ks = 1; ks < 4; ++ks) {
      U8 bh; ld_bfrag(bh, hp + 32 * ks);
      aR[rt] = MFMA(fh[0][ks], bh.v, aR[rt]);
      aZ[rt] = MFMA(fh[1][ks], bh.v, aZ[rt]);
      aN[rt] = MFMA(fh[2][ks], bh.v, aN[rt]);
    }
    aR[rt] = MFMA(fx[0], bx.v, aR[rt]);
    aZ[rt] = MFMA(fx[1], bx.v, aZ[rt]);
    aX[rt] = MFMA(fx[2], bx.v, bnx);
  }
  #pragma unroll
  for (int rt = 0; rt < 4; ++rt) {
    #pragma unroll
    for (int i = 0; i < 4; ++i) {
      float r = sigm(aR[rt][i]);
      float z = sigm(aZ[rt][i]);
      float n = tanh_(aX[rt][i] + r * aN[rt][i]);
      hn[rt][i] = z * (h_old[rt][i] - n) + n;
    }
  }
}

__device__ __forceinline__ void write_h(unsigned short* hd, const float (&v)[4][4],
                                        int w, int lr, int lg) {
  #pragma unroll
  for (int rt = 0; rt < 4; ++rt) {
    uint2 t;
    t.x = (unsigned)f2bf(v[rt][0]) | ((unsigned)f2bf(v[rt][1]) << 16);
    t.y = (unsigned)f2bf(v[rt][2]) | ((unsigned)f2bf(v[rt][3]) << 16);
    *(uint2*)(hd + (rt * 16 + lr) * HPAD + 16 * w + 4 * lg) = t;
  }
}

__global__ __launch_bounds__(NTHREADS, 2) void trace_gru_kernel(
    const float* __restrict__ obs, const float* __restrict__ target,
    const int* __restrict__ ids,
    const float* __restrict__ eWih, const float* __restrict__ eWhh,
    const float* __restrict__ ebih, const float* __restrict__ ebhh,
    const float* __restrict__ cWih, const float* __restrict__ cWhh,
    const float* __restrict__ cbih, const float* __restrict__ cbhh,
    const float* __restrict__ headW, const float* __restrict__ headb,
    const float* __restrict__ ppW1, const float* __restrict__ ppb1,
    const float* __restrict__ ppW2, const float* __restrict__ ppb2,
    const float* __restrict__ pkW1, const float* __restrict__ pkb1,
    const float* __restrict__ pkW2, const float* __restrict__ pkb2,
    float* __restrict__ out)
{
  __shared__ __align__(16) unsigned short h_lds[2][R_BLK * HPAD];
  __shared__ __align__(16) unsigned short x_lds[2][R_BLK * XPAD];
  __shared__ __align__(16) unsigned short a_lds[2 * R_BLK * APAD];
  __shared__ __align__(16) unsigned short wd_lds[12 * 64 * 8];

  const int tid = threadIdx.x;
  const int lane = tid & 63;
  const int w = tid >> 6;
  const int lr = lane & 15;
  const int lg = lane >> 4;
  const int row0 = blockIdx.x * R_BLK;

  {
    unsigned int* p = (unsigned int*)&h_lds[0][0];
    for (int i = tid; i < R_BLK * HPAD / 2; i += NTHREADS) p[i] = 0u;
    unsigned int* q = (unsigned int*)&x_lds[0][0];
    for (int i = tid; i < 2 * R_BLK * XPAD / 2; i += NTHREADS) q[i] = 0u;
  }
  __syncthreads();

  const int sx_row = tid / 5;
  const int sx_s = tid - 5 * sx_row;
  if (tid < 320)
    x_lds[0][sx_row * XPAD + sx_s] = f2bf(obs[(row0 + sx_row) * XSTR + sx_s]);

  float pmf[4], kmf[4];
  #pragma unroll
  for (int rt = 0; rt < 4; ++rt) {
    int id = ids[row0 + rt * 16 + lr];
    pmf[rt] = (id == 0) ? 1.0f : 0.0f;
    kmf[rt] = (id == 1) ? 1.0f : 0.0f;
  }

  short8 fh[3][4], fx[3];
  f32x4 brz0, brz1, bnh, bnx;
  #pragma unroll
  for (int mt = 0; mt < 3; ++mt) {
    #pragma unroll
    for (int ks = 0; ks < 4; ++ks)
      fh[mt][ks] = load_w(eWhh, H_DIM, mt * H_DIM + 16 * w, 384, H_DIM, ks, lr, lg);
    fx[mt] = load_w(eWih, S_DIM, mt * H_DIM + 16 * w, 384, S_DIM, 0, lr, lg);
  }
  #pragma unroll
  for (int i = 0; i < 4; ++i) {
    int g = 16 * w + 4 * lg + i;
    brz0[i] = ebih[g] + ebhh[g];
    brz1[i] = ebih[H_DIM + g] + ebhh[H_DIM + g];
    bnh[i]  = ebhh[2 * H_DIM + g];
    bnx[i]  = ebih[2 * H_DIM + g];
  }

  float h_reg[4][4];
  #pragma unroll
  for (int rt = 0; rt < 4; ++rt)
    #pragma unroll
    for (int i = 0; i < 4; ++i) h_reg[rt][i] = 0.0f;

  __syncthreads();

  // ---------------- encoder: 64 GRU steps ----------------
  for (int u = 0; u < T_OBS; ++u) {
    float hn[4][4];
    gru_step(h_lds[u & 1], x_lds[u & 1], fh, fx, brz0, brz1, bnh, bnx, h_reg, hn, lr, lg);
    #pragma unroll
    for (int rt = 0; rt < 4; ++rt)
      #pragma unroll
      for (int i = 0; i < 4; ++i) h_reg[rt][i] = hn[rt][i];
    write_h(h_lds[(u + 1) & 1], h_reg, w, lr, lg);
    if (tid < 320) {
      int un = u + 1;
      int tsrc = (un < T_OBS) ? un : (T_OBS - 1);
      x_lds[un & 1][sx_row * XPAD + sx_s] =
          f2bf(obs[(row0 + sx_row) * XSTR + tsrc * S_DIM + sx_s]);
    }
    __syncthreads();
  }

  // ---------------- decoder setup ----------------
  #pragma unroll
  for (int mt = 0; mt < 3; ++mt) {
    #pragma unroll
    for (int ks = 0; ks < 4; ++ks)
      fh[mt][ks] = load_w(cWhh, H_DIM, mt * H_DIM + 16 * w, 384, H_DIM, ks, lr, lg);
    fx[mt] = load_w(cWih, S_DIM, mt * H_DIM + 16 * w, 384, S_DIM, 0, lr, lg);
  }
  #pragma unroll
  for (int i = 0; i < 4; ++i) {
    int g = 16 * w + 4 * lg + i;
    brz0[i] = cbih[g] + cbhh[g];
    brz1[i] = cbih[H_DIM + g] + cbhh[H_DIM + g];
    bnh[i]  = cbhh[2 * H_DIM + g];
    bnx[i]  = cbih[2 * H_DIM + g];
  }
  short8 fW2[2];
  fW2[0] = load_w(ppW2, A_DIM, 16 * w, H_DIM, A_DIM, 0, lr, lg);
  fW2[1] = load_w(pkW2, A_DIM, 16 * w, H_DIM, A_DIM, 0, lr, lg);
  f32x4 b1v, b2v0, b2v1, hbv;
  {
    const float* b1p = (w & 1) ? pkb1 : ppb1;
    #pragma unroll
    for (int i = 0; i < 4; ++i) {
      b1v[i]  = b1p[4 * lg + i];
      b2v0[i] = ppb2[16 * w + 4 * lg + i];
      b2v1[i] = pkb2[16 * w + 4 * lg + i];
      int s = 4 * lg + i;
      hbv[i] = (s < S_DIM) ? headb[s] : 0.0f;
    }
  }
  for (int f = w; f < 12; f += 8) {
    short8 v;
    if (f < 8) {
      const float* W1 = (f >> 2) ? pkW1 : ppW1;
      v = load_w(W1, H_DIM, 0, A_DIM, H_DIM, f & 3, lr, lg);
    } else {
      v = load_w(headW, H_DIM, 0, S_DIM, H_DIM, f - 8, lr, lg);
    }
    *(short8*)&wd_lds[(f * 64 + lane) * 8] = v;
  }
  __syncthreads();

  // ---------------- decoder: 64 steps (GRU + adapter + head) ----------------
  for (int d = 0; d < F_FUT; ++d) {
    const int u = T_OBS + d;
    float hn[4][4];
    gru_step(h_lds[0], x_lds[u & 1], fh, fx, brz0, brz1, bnh, bnx, h_reg, hn, lr, lg);
    write_h(h_lds[1], hn, w, lr, lg);
    __syncthreads();  // BAR1: h_gru visible

    {   // adapter GEMM1: wave w -> adapter (w&1), row-tile (w>>1)
      const int aa = w & 1, art = w >> 1;
      const unsigned short* hp = &h_lds[1][(art * 16 + lr) * HPAD + 4 * lg];
      U8 bh0; ld_bfrag(bh0, hp);
      f32x4 acc = MFMA(*(const short8*)&wd_lds[((aa * 4 + 0) * 64 + lane) * 8], bh0.v, b1v);
      #pragma unroll
      for (int ks = 1; ks < 4; ++ks) {
        U8 bh; ld_bfrag(bh, hp + 32 * ks);
        acc = MFMA(*(const short8*)&wd_lds[((aa * 4 + ks) * 64 + lane) * 8], bh.v, acc);
      }
      uint2 t;
      t.x = (unsigned)f2bf(fmaxf(acc[0], 0.f)) | ((unsigned)f2bf(fmaxf(acc[1], 0.f)) << 16);
      t.y = (unsigned)f2bf(fmaxf(acc[2], 0.f)) | ((unsigned)f2bf(fmaxf(acc[3], 0.f)) << 16);
      *(uint2*)&a_lds[(aa * R_BLK + art * 16 + lr) * APAD + 4 * lg] = t;
    }
    __syncthreads();  // BAR2: a visible

    #pragma unroll
    for (int rt = 0; rt < 4; ++rt) {  // adapter GEMM2 + combine
      U8 b0, b1_;
      { uint2 t = *(const uint2*)&a_lds[(0 * R_BLK + rt * 16 + lr) * APAD + 4 * lg];
        b0.u[0] = t.x; b0.u[1] = t.y; b0.u[2] = 0u; b0.u[3] = 0u; }
      { uint2 t = *(const uint2*)&a_lds[(1 * R_BLK + rt * 16 + lr) * APAD + 4 * lg];
        b1_.u[0] = t.x; b1_.u[1] = t.y; b1_.u[2] = 0u; b1_.u[3] = 0u; }
      f32x4 d0 = MFMA(fW2[0], b0.v, b2v0);
      f32x4 d1 = MFMA(fW2[1], b1_.v, b2v1);
      #pragma unroll
      for (int i = 0; i < 4; ++i)
        h_reg[rt][i] = hn[rt][i] + pmf[rt] * d0[i] + kmf[rt] * d1[i];
    }
    write_h(h_lds[0], h_reg, w, lr, lg);
    if (d < F_FUT - 1 && tid < 320) {
      int un = u + 1;
      x_lds[un & 1][sx_row * XPAD + sx_s] =
          f2bf(target[(row0 + sx_row) * XSTR + (un - T_OBS - 1) * S_DIM + sx_s]);
    }
    __syncthreads();  // BAR3: h_final visible

    if (w < 4) {  // head: wave w handles row-tile w
      const unsigned short* hp = &h_lds[0][(w * 16 + lr) * HPAD + 4 * lg];
      U8 bh0; ld_bfrag(bh0, hp);
      f32x4 acc = MFMA(*(const short8*)&wd_lds[((8 + 0) * 64 + lane) * 8], bh0.v, hbv);
      #pragma unroll
      for (int ks = 1; ks < 4; ++ks) {
        U8 bh; ld_bfrag(bh, hp + 32 * ks);
        acc = MFMA(*(const short8*)&wd_lds[((8 + ks) * 64 + lane) * 8], bh.v, acc);
      }
      float* op = out + (size_t)((row0 + w * 16 + lr) * F_FUT + d) * S_DIM;
      if (lg == 0) { op[0] = acc[0]; op[1] = acc[1]; op[2] = acc[2]; op[3] = acc[3]; }
      else if (lg == 1) { op[4] = acc[0]; }
    }
  }
}

extern "C" void kernel_launch(void* const* d_in, const int* in_sizes, int n_in,
                              void* d_out, int out_size, void* d_ws, size_t ws_size,
                              hipStream_t stream) {
  (void)in_sizes; (void)n_in; (void)out_size; (void)d_ws; (void)ws_size;
  const float* obs    = (const float*)d_in[0];
  const float* target = (const float*)d_in[1];
  const int*   ids    = (const int*)d_in[2];
  const float* eWih = (const float*)d_in[3];
  const float* eWhh = (const float*)d_in[4];
  const float* ebih = (const float*)d_in[5];
  const float* ebhh = (const float*)d_in[6];
  const float* cWih = (const float*)d_in[7];
  const float* cWhh = (const float*)d_in[8];
  const float* cbih = (const float*)d_in[9];
  const float* cbhh = (const float*)d_in[10];
  const float* headW = (const float*)d_in[11];
  const float* headb = (const float*)d_in[12];
  const float* ppW1 = (const float*)d_in[13];
  const float* ppb1 = (const float*)d_in[14];
  const float* ppW2 = (const float*)d_in[15];
  const float* ppb2 = (const float*)d_in[16];
  const float* pkW1 = (const float*)d_in[17];
  const float* pkb1 = (const float*)d_in[18];
  const float* pkW2 = (const float*)d_in[19];
  const float* pkb2 = (const float*)d_in[20];

  dim3 grid(B_TOT / R_BLK), block(NTHREADS);
  trace_gru_kernel<<<grid, block, 0, stream>>>(
      obs, target, ids,
      eWih, eWhh, ebih, ebhh,
      cWih, cWhh, cbih, cbhh,
      headW, headb,
      ppW1, ppb1, ppW2, ppb2,
      pkW1, pkb1, pkW2, pkb2,
      (float*)d_out);
}

// Round 2
// 668.547 us; speedup vs baseline: 1.1867x; 1.1867x over previous
//
#include <hip/hip_runtime.h>

#define B_TOT 32768
#define T_OBS 64
#define F_FUT 64
#define S_DIM 5
#define H_DIM 128
#define A_DIM 16
#define R_BLK 64
#define NTHREADS 512
#define XSTR 320     // T*S row stride of obs/target (floats)
#define HSTR 128     // h LDS row stride (shorts): fragment-packed, lr-rotated 16B chunks
#define XPAD 36      // x LDS row stride (shorts)
#define APAD 24      // adapter LDS row stride (shorts)

#define LOG2E 1.4426950408889634f
#define L2E2  2.8853900817779268f

typedef __attribute__((ext_vector_type(8))) short short8;
typedef __attribute__((ext_vector_type(4))) float f32x4;

union U8 { short8 v; unsigned int u[4]; unsigned short s[8]; };

#if __has_builtin(__builtin_amdgcn_exp2f)
#define EXP2(x) __builtin_amdgcn_exp2f(x)
#else
#define EXP2(x) exp2f(x)
#endif

__device__ __forceinline__ unsigned short f2bf(float f) {
  unsigned int u = __float_as_uint(f);
  u += 0x7FFFu + ((u >> 16) & 1u);   // RNE
  return (unsigned short)(u >> 16);
}

__device__ __forceinline__ unsigned cvtpk(float a, float b) {
  unsigned r;
  asm("v_cvt_pk_bf16_f32 %0, %1, %2" : "=v"(r) : "v"(a), "v"(b));
  return r;
}

__device__ __forceinline__ f32x4 MFMA(short8 a, short8 b, f32x4 c) {
  return __builtin_amdgcn_mfma_f32_16x16x32_bf16(a, b, c, 0, 0, 0);
}

// ---- h LDS layout: row stride 128 shorts, fragment-packed:
// for k = 32*ks + 16*h + 4*g + j  ->  s = 32*ks + 8*g + 4*h + j
// 16B chunks (8 shorts) rotated by row&15 -> conflict-free b128 reads.
__device__ __forceinline__ short8 h_read(const unsigned short* base, int row, int ks, int lg) {
  return *(const short8*)(base + row * HSTR + (((4 * ks + lg + row) & 15) << 3));
}
__device__ __forceinline__ void h_write(unsigned short* base, int row, int w, int lg,
                                        unsigned lo, unsigned hi) {
  unsigned short* p = base + row * HSTR +
                      (((4 * (w >> 1) + lg + row) & 15) << 3) + ((w & 1) << 2);
  *(uint2*)p = make_uint2(lo, hi);
}

// A-fragment loader: rows g0+lr of row-major W[.][ld], scaled; k = 32ks+16(i>>2)+4lg+(i&3)
__device__ __forceinline__ short8 load_w(const float* __restrict__ W, int ld,
                                         int g0, int gmax, int kmax, int ks,
                                         int lr, int lg, float scale) {
  U8 a;
  const int g = g0 + lr;
  #pragma unroll
  for (int i = 0; i < 8; ++i) {
    int k = 32 * ks + 16 * (i >> 2) + 4 * lg + (i & 3);
    float v = (g < gmax && k < kmax) ? W[g * ld + k] * scale : 0.0f;
    a.s[i] = f2bf(v);
  }
  return a.v;
}

// teacher-forced x for logical step v in [0,128)
__device__ __forceinline__ float xload(const float* __restrict__ obs,
                                       const float* __restrict__ tgt,
                                       int row, int s, int v) {
  v = (v < 127) ? v : 127;
  if (v < 65) {
    int t = (v < 64) ? v : 63;
    return obs[(size_t)row * XSTR + t * S_DIM + s];
  }
  return tgt[(size_t)row * XSTR + (v - 65) * S_DIM + s];
}

__device__ __forceinline__ void gru_step(
    const unsigned short* __restrict__ hb, const unsigned short* __restrict__ xb,
    unsigned short* __restrict__ hd,
    const short8 (&fh)[3][4], const short8 (&fx)[3],
    const f32x4& brz0, const f32x4& brz1, const f32x4& bnh, const f32x4& bnx,
    float (&h_reg)[4][4], int w, int lr, int lg)
{
  #pragma unroll
  for (int rt = 0; rt < 4; ++rt) {
    const int row = rt * 16 + lr;
    U8 bx;
    { uint2 t = *(const uint2*)(xb + row * XPAD + 4 * lg);
      bx.u[0] = t.x; bx.u[1] = t.y; bx.u[2] = 0u; bx.u[3] = 0u; }
    short8 bh = h_read(hb, row, 0, lg);
    f32x4 aR = MFMA(fh[0][0], bh, brz0);
    f32x4 aZ = MFMA(fh[1][0], bh, brz1);
    f32x4 aN = MFMA(fh[2][0], bh, bnh);
    #pragma unroll
    for (int ks = 1; ks < 4; ++ks) {
      bh = h_read(hb, row, ks, lg);
      aR = MFMA(fh[0][ks], bh, aR);
      aZ = MFMA(fh[1][ks], bh, aZ);
      aN = MFMA(fh[2][ks], bh, aN);
    }
    aR = MFMA(fx[0], bx.v, aR);
    aZ = MFMA(fx[1], bx.v, aZ);
    f32x4 aX = MFMA(fx[2], bx.v, bnx);
    float hn0, hn1, hn2, hn3;
    #pragma unroll
    for (int i = 0; i < 4; ++i) {
      float r = __builtin_amdgcn_rcpf(1.0f + EXP2(-aR[i]));   // weights pre-scaled by log2e
      float z = __builtin_amdgcn_rcpf(1.0f + EXP2(-aZ[i]));
      float v = fmaf(r, aN[i], aX[i]);                        // pre-scaled by 2*log2e
      float q = __builtin_amdgcn_rcpf(1.0f + EXP2(-v));
      float n = fmaf(2.0f, q, -1.0f);                         // tanh
      float h = fmaf(z, h_reg[rt][i] - n, n);
      h_reg[rt][i] = h;
      if (i == 0) hn0 = h; else if (i == 1) hn1 = h; else if (i == 2) hn2 = h; else hn3 = h;
    }
    h_write(hd, row, w, lg, cvtpk(hn0, hn1), cvtpk(hn2, hn3));
  }
}

__global__ __launch_bounds__(NTHREADS, 2) void trace_gru_kernel(
    const float* __restrict__ obs, const float* __restrict__ target,
    const int* __restrict__ ids,
    const float* __restrict__ eWih, const float* __restrict__ eWhh,
    const float* __restrict__ ebih, const float* __restrict__ ebhh,
    const float* __restrict__ cWih, const float* __restrict__ cWhh,
    const float* __restrict__ cbih, const float* __restrict__ cbhh,
    const float* __restrict__ headW, const float* __restrict__ headb,
    const float* __restrict__ ppW1, const float* __restrict__ ppb1,
    const float* __restrict__ ppW2, const float* __restrict__ ppb2,
    const float* __restrict__ pkW1, const float* __restrict__ pkb1,
    const float* __restrict__ pkW2, const float* __restrict__ pkb2,
    float* __restrict__ out)
{
  __shared__ __align__(16) unsigned short h_lds[2][R_BLK * HSTR];
  __shared__ __align__(16) unsigned short x_lds[2][R_BLK * XPAD];
  __shared__ __align__(16) unsigned short a_lds[2 * R_BLK * APAD];
  __shared__ __align__(16) unsigned short wd_lds[12 * 64 * 8];

  const int tid = threadIdx.x;
  const int lane = tid & 63;
  const int w = tid >> 6;
  const int lr = lane & 15;
  const int lg = lane >> 4;
  const int row0 = blockIdx.x * R_BLK;

  {
    unsigned int* p = (unsigned int*)&h_lds[0][0];
    for (int i = tid; i < R_BLK * HSTR / 2; i += NTHREADS) p[i] = 0u;
    unsigned int* q = (unsigned int*)&x_lds[0][0];
    for (int i = tid; i < 2 * R_BLK * XPAD / 2; i += NTHREADS) q[i] = 0u;
  }
  __syncthreads();

  const bool xa = (tid < 320);
  const int sx_row = tid / 5;
  const int sx_s = tid - 5 * sx_row;
  float xe = 0.f;
  if (xa) {
    x_lds[0][sx_row * XPAD + sx_s] = f2bf(xload(obs, target, row0 + sx_row, sx_s, 0));
    xe = xload(obs, target, row0 + sx_row, sx_s, 1);
  }

  float pmf[4], kmf[4];
  #pragma unroll
  for (int rt = 0; rt < 4; ++rt) {
    int id = ids[row0 + rt * 16 + lr];
    pmf[rt] = (id == 0) ? 1.0f : 0.0f;
    kmf[rt] = (id == 1) ? 1.0f : 0.0f;
  }

  short8 fh[3][4], fx[3];
  f32x4 brz0, brz1, bnh, bnx;
  #pragma unroll
  for (int mt = 0; mt < 3; ++mt) {
    const float sc = (mt == 2) ? L2E2 : LOG2E;
    #pragma unroll
    for (int ks = 0; ks < 4; ++ks)
      fh[mt][ks] = load_w(eWhh, H_DIM, mt * H_DIM + 16 * w, 384, H_DIM, ks, lr, lg, sc);
    fx[mt] = load_w(eWih, S_DIM, mt * H_DIM + 16 * w, 384, S_DIM, 0, lr, lg, sc);
  }
  #pragma unroll
  for (int i = 0; i < 4; ++i) {
    int g = 16 * w + 4 * lg + i;
    brz0[i] = (ebih[g] + ebhh[g]) * LOG2E;
    brz1[i] = (ebih[H_DIM + g] + ebhh[H_DIM + g]) * LOG2E;
    bnh[i]  = ebhh[2 * H_DIM + g] * L2E2;
    bnx[i]  = ebih[2 * H_DIM + g] * L2E2;
  }

  float h_reg[4][4];
  #pragma unroll
  for (int rt = 0; rt < 4; ++rt)
    #pragma unroll
    for (int i = 0; i < 4; ++i) h_reg[rt][i] = 0.0f;

  __syncthreads();

  // ---------------- encoder: 64 GRU steps ----------------
  for (int u = 0; u < T_OBS; ++u) {
    float xn = 0.f;
    if (xa) xn = xload(obs, target, row0 + sx_row, sx_s, u + 2);   // 2-deep prefetch
    gru_step(&h_lds[u & 1][0], &x_lds[u & 1][0], &h_lds[(u + 1) & 1][0],
             fh, fx, brz0, brz1, bnh, bnx, h_reg, w, lr, lg);
    if (xa) x_lds[(u + 1) & 1][sx_row * XPAD + sx_s] = f2bf(xe);
    __syncthreads();
    xe = xn;
  }

  // ---------------- decoder setup ----------------
  #pragma unroll
  for (int mt = 0; mt < 3; ++mt) {
    const float sc = (mt == 2) ? L2E2 : LOG2E;
    #pragma unroll
    for (int ks = 0; ks < 4; ++ks)
      fh[mt][ks] = load_w(cWhh, H_DIM, mt * H_DIM + 16 * w, 384, H_DIM, ks, lr, lg, sc);
    fx[mt] = load_w(cWih, S_DIM, mt * H_DIM + 16 * w, 384, S_DIM, 0, lr, lg, sc);
  }
  #pragma unroll
  for (int i = 0; i < 4; ++i) {
    int g = 16 * w + 4 * lg + i;
    brz0[i] = (cbih[g] + cbhh[g]) * LOG2E;
    brz1[i] = (cbih[H_DIM + g] + cbhh[H_DIM + g]) * LOG2E;
    bnh[i]  = cbhh[2 * H_DIM + g] * L2E2;
    bnx[i]  = cbih[2 * H_DIM + g] * L2E2;
  }
  short8 fW2[2];
  fW2[0] = load_w(ppW2, A_DIM, 16 * w, H_DIM, A_DIM, 0, lr, lg, 1.0f);
  fW2[1] = load_w(pkW2, A_DIM, 16 * w, H_DIM, A_DIM, 0, lr, lg, 1.0f);
  f32x4 b1v, b2v0, b2v1, hbv;
  {
    const float* b1p = (w & 1) ? pkb1 : ppb1;
    #pragma unroll
    for (int i = 0; i < 4; ++i) {
      b1v[i]  = b1p[4 * lg + i];
      b2v0[i] = ppb2[16 * w + 4 * lg + i];
      b2v1[i] = pkb2[16 * w + 4 * lg + i];
      int s = 4 * lg + i;
      hbv[i] = (s < S_DIM) ? headb[s] : 0.0f;
    }
  }
  for (int f = w; f < 12; f += 8) {
    short8 v;
    if (f < 8) {
      const float* W1 = (f >> 2) ? pkW1 : ppW1;
      v = load_w(W1, H_DIM, 0, A_DIM, H_DIM, f & 3, lr, lg, 1.0f);
    } else {
      v = load_w(headW, H_DIM, 0, S_DIM, H_DIM, f - 8, lr, lg, 1.0f);
    }
    *(short8*)&wd_lds[(f * 64 + lane) * 8] = v;
  }
  __syncthreads();

  // ---------------- decoder: 64 steps (GRU + adapter + head) ----------------
  for (int d = 0; d < F_FUT; ++d) {
    const int u = T_OBS + d;
    float xn = 0.f;
    if (xa) xn = xload(obs, target, row0 + sx_row, sx_s, u + 2);
    gru_step(&h_lds[0][0], &x_lds[u & 1][0], &h_lds[1][0],
             fh, fx, brz0, brz1, bnh, bnx, h_reg, w, lr, lg);
    __syncthreads();  // BAR1: h_gru visible

    {   // adapter GEMM1: wave w -> adapter (w&1), row-tile (w>>1)
      const int aa = w & 1, art = w >> 1;
      const int arow = art * 16 + lr;
      short8 bh = h_read(&h_lds[1][0], arow, 0, lg);
      f32x4 acc = MFMA(*(const short8*)&wd_lds[((aa * 4 + 0) * 64 + lane) * 8], bh, b1v);
      #pragma unroll
      for (int ks = 1; ks < 4; ++ks) {
        bh = h_read(&h_lds[1][0], arow, ks, lg);
        acc = MFMA(*(const short8*)&wd_lds[((aa * 4 + ks) * 64 + lane) * 8], bh, acc);
      }
      unsigned lo = cvtpk(fmaxf(acc[0], 0.f), fmaxf(acc[1], 0.f));
      unsigned hi = cvtpk(fmaxf(acc[2], 0.f), fmaxf(acc[3], 0.f));
      *(uint2*)&a_lds[(aa * R_BLK + arow) * APAD + 4 * lg] = make_uint2(lo, hi);
    }
    __syncthreads();  // BAR2: a visible

    #pragma unroll
    for (int rt = 0; rt < 4; ++rt) {  // adapter GEMM2 + combine
      const int arow = rt * 16 + lr;
      U8 b0, b1_;
      { uint2 t = *(const uint2*)&a_lds[(0 * R_BLK + arow) * APAD + 4 * lg];
        b0.u[0] = t.x; b0.u[1] = t.y; b0.u[2] = 0u; b0.u[3] = 0u; }
      { uint2 t = *(const uint2*)&a_lds[(1 * R_BLK + arow) * APAD + 4 * lg];
        b1_.u[0] = t.x; b1_.u[1] = t.y; b1_.u[2] = 0u; b1_.u[3] = 0u; }
      f32x4 d0 = MFMA(fW2[0], b0.v, b2v0);
      f32x4 d1 = MFMA(fW2[1], b1_.v, b2v1);
      float hv0, hv1, hv2, hv3;
      #pragma unroll
      for (int i = 0; i < 4; ++i) {
        float h = h_reg[rt][i] + pmf[rt] * d0[i] + kmf[rt] * d1[i];
        h_reg[rt][i] = h;
        if (i == 0) hv0 = h; else if (i == 1) hv1 = h; else if (i == 2) hv2 = h; else hv3 = h;
      }
      h_write(&h_lds[0][0], arow, w, lg, cvtpk(hv0, hv1), cvtpk(hv2, hv3));
    }
    if (xa) x_lds[(u + 1) & 1][sx_row * XPAD + sx_s] = f2bf(xe);
    __syncthreads();  // BAR3: h_final visible

    if (w < 4) {  // head: wave w handles row-tile w
      const int arow = w * 16 + lr;
      short8 bh = h_read(&h_lds[0][0], arow, 0, lg);
      f32x4 acc = MFMA(*(const short8*)&wd_lds[((8 + 0) * 64 + lane) * 8], bh, hbv);
      #pragma unroll
      for (int ks = 1; ks < 4; ++ks) {
        bh = h_read(&h_lds[0][0], arow, ks, lg);
        acc = MFMA(*(const short8*)&wd_lds[((8 + ks) * 64 + lane) * 8], bh, acc);
      }
      float* op = out + (size_t)((row0 + arow) * F_FUT + d) * S_DIM;
      if (lg == 0) { op[0] = acc[0]; op[1] = acc[1]; op[2] = acc[2]; op[3] = acc[3]; }
      else if (lg == 1) { op[4] = acc[0]; }
    }
    xe = xn;
  }
}

extern "C" void kernel_launch(void* const* d_in, const int* in_sizes, int n_in,
                              void* d_out, int out_size, void* d_ws, size_t ws_size,
                              hipStream_t stream) {
  (void)in_sizes; (void)n_in; (void)out_size; (void)d_ws; (void)ws_size;
  const float* obs    = (const float*)d_in[0];
  const float* target = (const float*)d_in[1];
  const int*   ids    = (const int*)d_in[2];
  const float* eWih = (const float*)d_in[3];
  const float* eWhh = (const float*)d_in[4];
  const float* ebih = (const float*)d_in[5];
  const float* ebhh = (const float*)d_in[6];
  const float* cWih = (const float*)d_in[7];
  const float* cWhh = (const float*)d_in[8];
  const float* cbih = (const float*)d_in[9];
  const float* cbhh = (const float*)d_in[10];
  const float* headW = (const float*)d_in[11];
  const float* headb = (const float*)d_in[12];
  const float* ppW1 = (const float*)d_in[13];
  const float* ppb1 = (const float*)d_in[14];
  const float* ppW2 = (const float*)d_in[15];
  const float* ppb2 = (const float*)d_in[16];
  const float* pkW1 = (const float*)d_in[17];
  const float* pkb1 = (const float*)d_in[18];
  const float* pkW2 = (const float*)d_in[19];
  const float* pkb2 = (const float*)d_in[20];

  dim3 grid(B_TOT / R_BLK), block(NTHREADS);
  trace_gru_kernel<<<grid, block, 0, stream>>>(
      obs, target, ids,
      eWih, eWhh, ebih, ebhh,
      cWih, cWhh, cbih, cbhh,
      headW, headb,
      ppW1, ppb1, ppW2, ppb2,
      pkW1, pkb1, pkW2, pkb2,
      (float*)d_out);
}